// Round 12
// baseline (47.723 us; speedup 1.0000x reference)
//
#include <hip/hip_runtime.h>
#include <math.h>

#define INV_TWO_PI_F 0.15915494309189535f

// Hardware sin/cos take REVOLUTIONS: v_sin(r) = sin(2*pi*r). Reduce with fract.
__device__ __forceinline__ void sincos_rev(float rev, float* s, float* c) {
    float r = rev - floorf(rev);
    *s = __builtin_amdgcn_sinf(r);
    *c = __builtin_amdgcn_cosf(r);
}

// ---------------------------------------------------------------------------
// Kernel 1: per-station coefficients -> d_ws (1.6 MB, proven to fit in R1).
// pq[n*8+{0..3}] = {P0,Q0,P1,Q1}, pq[n*8+{4..7}] = {P2,Q2,P3,Q3}
//   P_i = s_amp*mr/|m| (sin coeff), Q_i = s_amp*mi/|m| (cos coeff)
// ---------------------------------------------------------------------------
template <int KT>
__global__ __launch_bounds__(256) void k_coef(
        const float* __restrict__ amp,  const float* __restrict__ ph,
        const float* __restrict__ w,    const int* __restrict__ nbr,
        const float* __restrict__ bmin, const float* __restrict__ bmax,
        float* __restrict__ pq, int N, int Krt) {
    const int n = blockIdx.x * blockDim.x + threadIdx.x;
    if (n >= N) return;
    const int K = KT ? KT : Krt;

    float na[4] = {0.f, 0.f, 0.f, 0.f};
    float ar[4] = {0.f, 0.f, 0.f, 0.f};
    float ai[4] = {0.f, 0.f, 0.f, 0.f};
#pragma unroll
    for (int k = 0; k < K; ++k) {
        const float wk = w[(size_t)n * K + k];
        const int   m  = nbr[(size_t)n * K + k];
        const float4 am = *(const float4*)(amp + (size_t)m * 4);
        const float4 pm = *(const float4*)(ph + (size_t)m * 4);
        const float amv[4] = {am.x, am.y, am.z, am.w};
        const float pmv[4] = {pm.x, pm.y, pm.z, pm.w};
#pragma unroll
        for (int i = 0; i < 4; ++i) {
            float s, c;
            sincos_rev(pmv[i] * INV_TWO_PI_F, &s, &c);
            na[i] = fmaf(amv[i], wk, na[i]);
            ar[i] = fmaf(c, wk, ar[i]);
            ai[i] = fmaf(s, wk, ai[i]);
        }
    }
    const float4 a0 = *(const float4*)(amp + (size_t)n * 4);
    const float4 p0 = *(const float4*)(ph + (size_t)n * 4);
    const float av[4] = {a0.x, a0.y, a0.z, a0.w};
    const float pv[4] = {p0.x, p0.y, p0.z, p0.w};
    float o[8];
#pragma unroll
    for (int i = 0; i < 4; ++i) {
        float s_amp = fmaf(0.15f, na[i], 0.85f * av[i]);
        s_amp = fminf(fmaxf(s_amp, bmin[(size_t)i * N + n]),
                      bmax[(size_t)i * N + n]);
        float ci, cr;
        sincos_rev(pv[i] * INV_TWO_PI_F, &ci, &cr);
        const float mr  = fmaf(0.1f, ar[i], 0.9f * cr);
        const float mi  = fmaf(0.1f, ai[i], 0.9f * ci);
        const float inv = rsqrtf(fmaf(mr, mr, mi * mi));  // |m| >= 0.8
        o[2 * i]     = s_amp * mr * inv;
        o[2 * i + 1] = s_amp * mi * inv;
    }
    float4 o0; o0.x = o[0]; o0.y = o[1]; o0.z = o[2]; o0.w = o[3];
    float4 o1; o1.x = o[4]; o1.y = o[5]; o1.z = o[6]; o1.w = o[7];
    *(float4*)(pq + (size_t)n * 8)     = o0;
    *(float4*)(pq + (size_t)n * 8 + 4) = o1;
}

// ---------------------------------------------------------------------------
// Kernel 2: sweep. R8's exact burst structure (ROWS=50, U=10, 4 blk/CU) but
// ZERO LDS and ZERO __syncthreads: per-row coefficients come from global via
// block-uniform addresses -> compiler emits scalar s_load (SMEM pipe, SGPR
// broadcast). Hot loop = pure VALU + burst stores, fill-kernel shape.
//   out[n*T+t] = c0 + b*tv[t] + sum_i (P_i*sin(2pi f_i tv[t]) + Q_i*cos(...))
// ---------------------------------------------------------------------------
template <int ROWS, int U>
__global__ __launch_bounds__(256, 4) void k_sweep(
        const float* __restrict__ tv, const float* __restrict__ co,
        const float* __restrict__ lt, const float* __restrict__ pq,
        float* __restrict__ out, int N, int T) {
    const int tid   = threadIdx.x;
    const int nq    = (T + 3) >> 2;
    const int qi    = blockIdx.y * 256 + tid;
    const int t0    = qi * 4;
    const bool act  = (qi < nq);
    const int nbase = blockIdx.x * ROWS;

    // ---- Table: 4 consecutive t per thread, 4 periods (hw v_sin/v_cos) ----
    const float freqs[4] = {4.0f, 2.0f, 1.0f, 0.5f};
    float tvq[4], sn[4][4], cs[4][4];
#pragma unroll
    for (int q = 0; q < 4; ++q) {
        int t = t0 + q; if (t > T - 1) t = T - 1;
        tvq[q] = tv[t];
#pragma unroll
        for (int i = 0; i < 4; ++i)
            sincos_rev(freqs[i] * tvq[q], &sn[q][i], &cs[q][i]);
    }

    if (!act) return;

    float* dst = out + (size_t)nbase * T + t0;
#pragma unroll 1
    for (int rb = 0; rb < ROWS; rb += U) {
        float v[U][4];
#pragma unroll
        for (int u = 0; u < U; ++u) {
            const int n = nbase + rb + u;            // block-uniform
            const float4 PQ0 = *(const float4*)(pq + (size_t)n * 8);
            const float4 PQ1 = *(const float4*)(pq + (size_t)n * 8 + 4);
            const float  c0  = co[n];
            const float  b   = lt[n];
#pragma unroll
            for (int q = 0; q < 4; ++q) {
                float x = fmaf(b, tvq[q], c0);
                x = fmaf(PQ0.x, sn[q][0], x);
                x = fmaf(PQ0.y, cs[q][0], x);
                x = fmaf(PQ0.z, sn[q][1], x);
                x = fmaf(PQ0.w, cs[q][1], x);
                x = fmaf(PQ1.x, sn[q][2], x);
                x = fmaf(PQ1.y, cs[q][2], x);
                x = fmaf(PQ1.z, sn[q][3], x);
                x = fmaf(PQ1.w, cs[q][3], x);
                v[u][q] = x;
            }
        }
        // burst-store U rows back-to-back
        if (t0 + 3 < T) {
#pragma unroll
            for (int u = 0; u < U; ++u) {
                const int n = nbase + rb + u;
                if (n >= N) break;
                float4 o; o.x = v[u][0]; o.y = v[u][1]; o.z = v[u][2]; o.w = v[u][3];
                *(float4*)(dst + (size_t)(rb + u) * T) = o;
            }
        } else {
#pragma unroll
            for (int u = 0; u < U; ++u) {
                const int n = nbase + rb + u;
                if (n >= N) break;
#pragma unroll
                for (int q = 0; q < 4; ++q)
                    if (t0 + q < T) *(dst + (size_t)(rb + u) * T + q) = v[u][q];
            }
        }
    }
}

extern "C" void kernel_launch(void* const* d_in, const int* in_sizes, int n_in,
                              void* d_out, int out_size, void* d_ws, size_t ws_size,
                              hipStream_t stream) {
    const float* tv   = (const float*)d_in[0];
    const float* co   = (const float*)d_in[1];
    const float* lt   = (const float*)d_in[2];
    const float* amp  = (const float*)d_in[3];
    const float* ph   = (const float*)d_in[4];
    const float* w    = (const float*)d_in[5];
    const float* bmin = (const float*)d_in[6];
    const float* bmax = (const float*)d_in[7];
    const int*   nbr  = (const int*)d_in[8];

    const int T = in_sizes[0];
    const int N = in_sizes[1];
    const int K = in_sizes[5] / N;

    float* pq  = (float*)d_ws;       // N*8 floats = 1.6 MB (fits, proven R1)
    float* out = (float*)d_out;

    if (K == 8) {
        k_coef<8><<<(N + 255) / 256, 256, 0, stream>>>(amp, ph, w, nbr, bmin,
                                                       bmax, pq, N, K);
    } else {
        k_coef<0><<<(N + 255) / 256, 256, 0, stream>>>(amp, ph, w, nbr, bmin,
                                                       bmax, pq, N, K);
    }

    constexpr int ROWS = 50;   // 1000 blocks
    constexpr int U    = 10;   // R8-validated burst depth
    const int nq = (T + 3) / 4;
    dim3 grid((N + ROWS - 1) / ROWS, (nq + 255) / 256);
    k_sweep<ROWS, U><<<grid, 256, 0, stream>>>(tv, co, lt, pq, out, N, T);
}